// Round 2
// baseline (19701.712 us; speedup 1.0000x reference)
//
#include <hip/hip_runtime.h>
#include <math.h>

// Problem constants
#define NCH   128          // chains = 2*B (0..63 = generated, 64..127 = true)
#define SLEN  256
#define HDIM  1024
#define N3    3072

// ---------------------------------------------------------------------------
// xproj: out[r, n] = x_row(r) @ W[n, :] + bias[n]   for r in [0, 128*gridDim.y)
// Row mapping: chain = r >> lTc, dt = r & (Tc-1);
//   src row = chain*strideChain + t0 + dt  (A0 if chain<chainsA0 else A1).
// 128x128 tile, BK=16, 256 threads, 8x8 per thread. fp32.
// ---------------------------------------------------------------------------
__global__ __launch_bounds__(256) void xproj_gemm(
    const float* __restrict__ A0, const float* __restrict__ A1,
    int chainsA0, int strideChain, int t0, int K, int lTc,
    const float* __restrict__ W, const float* __restrict__ bias, float* __restrict__ out)
{
  __shared__ __align__(16) float As[16][132];
  __shared__ __align__(16) float Bs[16][132];
  const int tid  = threadIdx.x;
  const int col0 = blockIdx.x * 128;
  const int row0 = blockIdx.y * 128;
  const int tm0  = (tid & 15) * 8;
  const int tn0  = (tid >> 4) * 8;
  const int lr   = tid >> 1;
  const int lk   = (tid & 1) * 8;
  const int r     = row0 + lr;
  const int chain = r >> lTc;
  const int dt    = r & ((1 << lTc) - 1);
  const float* aptr = (chain < chainsA0)
      ? (A0 + ((size_t)chain * strideChain + t0 + dt) * K)
      : (A1 + ((size_t)(chain - chainsA0) * strideChain + t0 + dt) * K);
  const float* bptr = W + (size_t)(col0 + lr) * K;

  float acc[8][8];
#pragma unroll
  for (int i = 0; i < 8; ++i)
#pragma unroll
    for (int j = 0; j < 8; ++j) acc[i][j] = 0.f;

  for (int k0 = 0; k0 < K; k0 += 16) {
    float4 av0 = *(const float4*)(aptr + k0 + lk);
    float4 av1 = *(const float4*)(aptr + k0 + lk + 4);
    float4 bv0 = *(const float4*)(bptr + k0 + lk);
    float4 bv1 = *(const float4*)(bptr + k0 + lk + 4);
    __syncthreads();
    As[lk+0][lr]=av0.x; As[lk+1][lr]=av0.y; As[lk+2][lr]=av0.z; As[lk+3][lr]=av0.w;
    As[lk+4][lr]=av1.x; As[lk+5][lr]=av1.y; As[lk+6][lr]=av1.z; As[lk+7][lr]=av1.w;
    Bs[lk+0][lr]=bv0.x; Bs[lk+1][lr]=bv0.y; Bs[lk+2][lr]=bv0.z; Bs[lk+3][lr]=bv0.w;
    Bs[lk+4][lr]=bv1.x; Bs[lk+5][lr]=bv1.y; Bs[lk+6][lr]=bv1.z; Bs[lk+7][lr]=bv1.w;
    __syncthreads();
#pragma unroll
    for (int kk = 0; kk < 16; ++kk) {
      float4 a0 = *(const float4*)&As[kk][tm0];
      float4 a1 = *(const float4*)&As[kk][tm0+4];
      float4 b0 = *(const float4*)&Bs[kk][tn0];
      float4 b1 = *(const float4*)&Bs[kk][tn0+4];
      float am[8] = {a0.x,a0.y,a0.z,a0.w,a1.x,a1.y,a1.z,a1.w};
      float bn[8] = {b0.x,b0.y,b0.z,b0.w,b1.x,b1.y,b1.z,b1.w};
#pragma unroll
      for (int i = 0; i < 8; ++i)
#pragma unroll
        for (int j = 0; j < 8; ++j) acc[i][j] = fmaf(am[i], bn[j], acc[i][j]);
    }
  }
#pragma unroll
  for (int i = 0; i < 8; ++i) {
    const int row = row0 + tm0 + i;
    float* orow = out + (size_t)row * N3 + col0 + tn0;
    const float* brow = bias + col0 + tn0;
    float4 b0 = *(const float4*)(brow);
    float4 b1 = *(const float4*)(brow + 4);
    float4 c0 = make_float4(acc[i][0]+b0.x, acc[i][1]+b0.y, acc[i][2]+b0.z, acc[i][3]+b0.w);
    float4 c1 = make_float4(acc[i][4]+b1.x, acc[i][5]+b1.y, acc[i][6]+b1.z, acc[i][7]+b1.w);
    *(float4*)(orow)     = c0;
    *(float4*)(orow + 4) = c1;
  }
}

// ---------------------------------------------------------------------------
// ln_rows: in-place LayerNorm per gate over H for each row of [rows, 3, H].
// ---------------------------------------------------------------------------
__global__ __launch_bounds__(256) void ln_rows(float* __restrict__ a,
    const float* __restrict__ gw, const float* __restrict__ gb)
{
  const int row = blockIdx.x;
  const int tid = threadIdx.x;
  float* base = a + (size_t)row * N3;
  __shared__ float redS[4], redS2[4];
  __shared__ float s_mean, s_rstd;
  for (int g = 0; g < 3; ++g) {
    const int j = g * 1024 + tid * 4;
    float4 v = *(const float4*)(base + j);
    float s  = v.x + v.y + v.z + v.w;
    float s2 = v.x*v.x + v.y*v.y + v.z*v.z + v.w*v.w;
#pragma unroll
    for (int off = 32; off > 0; off >>= 1) {
      s  += __shfl_down(s, off);
      s2 += __shfl_down(s2, off);
    }
    if ((tid & 63) == 0) { redS[tid >> 6] = s; redS2[tid >> 6] = s2; }
    __syncthreads();
    if (tid == 0) {
      float S  = redS[0] + redS[1] + redS[2] + redS[3];
      float S2 = redS2[0] + redS2[1] + redS2[2] + redS2[3];
      float mean = S * (1.f / 1024.f);
      float var  = S2 * (1.f / 1024.f) - mean * mean;
      s_mean = mean;
      s_rstd = rsqrtf(var + 1e-5f);
    }
    __syncthreads();
    float mean = s_mean, rstd = s_rstd;
    float4 gwv = *(const float4*)(gw + j);
    float4 gbv = *(const float4*)(gb + j);
    float4 o;
    o.x = (v.x - mean) * rstd * gwv.x + gbv.x;
    o.y = (v.y - mean) * rstd * gwv.y + gbv.y;
    o.z = (v.z - mean) * rstd * gwv.z + gbv.z;
    o.w = (v.w - mean) * rstd * gwv.w + gbv.w;
    *(float4*)(base + j) = o;
    __syncthreads();
  }
}

// ---------------------------------------------------------------------------
// gemm_step: ah_part[kc][m][n] = h[m, kc*256:+256] @ Whh[n, same]^T
// Split-K=4, grid 48x4 = 192 blocks. 128x64 tile, 256 thr, 8x4/thread.
// ---------------------------------------------------------------------------
__global__ __launch_bounds__(256) void gemm_step(
    const float* __restrict__ h, const float* __restrict__ Whh, float* __restrict__ ah_part)
{
  __shared__ __align__(16) float As[16][132];
  __shared__ __align__(16) float Bs[16][68];
  const int tid = threadIdx.x;
  const int n0  = blockIdx.x * 64;
  const int kc  = blockIdx.y;
  const int tm0 = (tid & 15) * 8;
  const int tn0 = (tid >> 4) * 4;
  const int lr  = tid >> 1;
  const int lk  = (tid & 1) * 8;
  const int lb  = tid >> 2;
  const int lkb = (tid & 3) * 4;
  const float* aptr = h + (size_t)lr * HDIM;
  const float* bptr = Whh + (size_t)(n0 + lb) * HDIM;

  float acc[8][4];
#pragma unroll
  for (int i = 0; i < 8; ++i)
#pragma unroll
    for (int j = 0; j < 4; ++j) acc[i][j] = 0.f;

  const int kbase = kc * 256;
  for (int k0 = kbase; k0 < kbase + 256; k0 += 16) {
    float4 av0 = *(const float4*)(aptr + k0 + lk);
    float4 av1 = *(const float4*)(aptr + k0 + lk + 4);
    float4 bv  = *(const float4*)(bptr + k0 + lkb);
    __syncthreads();
    As[lk+0][lr]=av0.x; As[lk+1][lr]=av0.y; As[lk+2][lr]=av0.z; As[lk+3][lr]=av0.w;
    As[lk+4][lr]=av1.x; As[lk+5][lr]=av1.y; As[lk+6][lr]=av1.z; As[lk+7][lr]=av1.w;
    Bs[lkb+0][lb]=bv.x; Bs[lkb+1][lb]=bv.y; Bs[lkb+2][lb]=bv.z; Bs[lkb+3][lb]=bv.w;
    __syncthreads();
#pragma unroll
    for (int kk = 0; kk < 16; ++kk) {
      float4 a0 = *(const float4*)&As[kk][tm0];
      float4 a1 = *(const float4*)&As[kk][tm0+4];
      float4 b  = *(const float4*)&Bs[kk][tn0];
      float am[8] = {a0.x,a0.y,a0.z,a0.w,a1.x,a1.y,a1.z,a1.w};
      float bn[4] = {b.x,b.y,b.z,b.w};
#pragma unroll
      for (int i = 0; i < 8; ++i)
#pragma unroll
        for (int j = 0; j < 4; ++j) acc[i][j] = fmaf(am[i], bn[j], acc[i][j]);
    }
  }
#pragma unroll
  for (int i = 0; i < 8; ++i) {
    const int m = tm0 + i;
    *(float4*)(ah_part + ((size_t)(kc * 128 + m)) * N3 + n0 + tn0) =
        make_float4(acc[i][0], acc[i][1], acc[i][2], acc[i][3]);
  }
}

// ---------------------------------------------------------------------------
// lngate_step: per chain -- sum split-K partials + bhh, LN per gate, combine
// with pi row (chain*Tc + dt), GRU gates, write h_cur (+ optional h-seq row).
// ---------------------------------------------------------------------------
__global__ __launch_bounds__(256) void lngate_step(
    const float* __restrict__ ah_part, const float* __restrict__ bhh,
    const float* __restrict__ ghw, const float* __restrict__ ghb,
    const float* __restrict__ pi, int Tc, int dt, float* __restrict__ h_cur,
    float* __restrict__ hseq)
{
  const int c   = blockIdx.x;
  const int tid = threadIdx.x;
  __shared__ __align__(16) float sa[N3];
  __shared__ float redS[4], redS2[4];
  __shared__ float stats[3][2];

#pragma unroll
  for (int p = 0; p < 3; ++p) {
    const int n = p * 1024 + tid * 4;
    float4 v0 = *(const float4*)(ah_part + ((size_t)(0 * 128 + c)) * N3 + n);
    float4 v1 = *(const float4*)(ah_part + ((size_t)(1 * 128 + c)) * N3 + n);
    float4 v2 = *(const float4*)(ah_part + ((size_t)(2 * 128 + c)) * N3 + n);
    float4 v3 = *(const float4*)(ah_part + ((size_t)(3 * 128 + c)) * N3 + n);
    float4 bb = *(const float4*)(bhh + n);
    float4 s;
    s.x = v0.x + v1.x + v2.x + v3.x + bb.x;
    s.y = v0.y + v1.y + v2.y + v3.y + bb.y;
    s.z = v0.z + v1.z + v2.z + v3.z + bb.z;
    s.w = v0.w + v1.w + v2.w + v3.w + bb.w;
    *(float4*)(sa + n) = s;
  }
  __syncthreads();

  for (int g = 0; g < 3; ++g) {
    float4 v = *(const float4*)(sa + g * 1024 + tid * 4);
    float s  = v.x + v.y + v.z + v.w;
    float s2 = v.x*v.x + v.y*v.y + v.z*v.z + v.w*v.w;
#pragma unroll
    for (int off = 32; off > 0; off >>= 1) {
      s  += __shfl_down(s, off);
      s2 += __shfl_down(s2, off);
    }
    if ((tid & 63) == 0) { redS[tid >> 6] = s; redS2[tid >> 6] = s2; }
    __syncthreads();
    if (tid == 0) {
      float S  = redS[0] + redS[1] + redS[2] + redS[3];
      float S2 = redS2[0] + redS2[1] + redS2[2] + redS2[3];
      float mean = S * (1.f / 1024.f);
      float var  = S2 * (1.f / 1024.f) - mean * mean;
      stats[g][0] = mean;
      stats[g][1] = rsqrtf(var + 1e-5f);
    }
    __syncthreads();
  }

  const int j = tid * 4;
  float ar[4], az[4], an[4];
  *(float4*)ar = *(const float4*)(sa + j);
  *(float4*)az = *(const float4*)(sa + 1024 + j);
  *(float4*)an = *(const float4*)(sa + 2048 + j);
  float gwr[4], gbr[4], gwz[4], gbz[4], gwn[4], gbn[4];
  *(float4*)gwr = *(const float4*)(ghw + j);
  *(float4*)gbr = *(const float4*)(ghb + j);
  *(float4*)gwz = *(const float4*)(ghw + 1024 + j);
  *(float4*)gbz = *(const float4*)(ghb + 1024 + j);
  *(float4*)gwn = *(const float4*)(ghw + 2048 + j);
  *(float4*)gbn = *(const float4*)(ghb + 2048 + j);
  const float* pirow = pi + ((size_t)c * Tc + dt) * N3;
  float pr[4], pz[4], pn[4], hp[4], hn[4];
  *(float4*)pr = *(const float4*)(pirow + j);
  *(float4*)pz = *(const float4*)(pirow + 1024 + j);
  *(float4*)pn = *(const float4*)(pirow + 2048 + j);
  *(float4*)hp = *(const float4*)(h_cur + (size_t)c * HDIM + j);
  const float mr = stats[0][0], rr = stats[0][1];
  const float mz = stats[1][0], rz = stats[1][1];
  const float mn = stats[2][0], rn = stats[2][1];
#pragma unroll
  for (int q = 0; q < 4; ++q) {
    float phr = (ar[q] - mr) * rr * gwr[q] + gbr[q];
    float phz = (az[q] - mz) * rz * gwz[q] + gbz[q];
    float phn = (an[q] - mn) * rn * gwn[q] + gbn[q];
    float r = 1.f / (1.f + expf(-(pr[q] + phr)));
    float z = 1.f / (1.f + expf(-(pz[q] + phz)));
    float nn = tanhf(pn[q] + r * phn);
    hn[q] = (1.f - z) * nn + z * hp[q];
  }
  *(float4*)(h_cur + (size_t)c * HDIM + j) = *(float4*)hn;
  if (hseq)
    *(float4*)(hseq + ((size_t)c * Tc + dt) * HDIM + j) = *(float4*)hn;
}

// ---------------------------------------------------------------------------
__global__ void zero_kernel(float* __restrict__ p, int n)
{
  int i = blockIdx.x * blockDim.x + threadIdx.x;
  if (i < n) p[i] = 0.f;
}

__global__ __launch_bounds__(256) void label_kernel(const float* __restrict__ h,
    const float* __restrict__ Wout, const float* __restrict__ bout,
    float* __restrict__ labels)
{
  const int c = blockIdx.x;
  const int tid = threadIdx.x;
  __shared__ float red[4];
  float4 hv = *(const float4*)(h + (size_t)c * HDIM + tid * 4);
  float4 wv = *(const float4*)(Wout + tid * 4);
  float s = hv.x * wv.x + hv.y * wv.y + hv.z * wv.z + hv.w * wv.w;
#pragma unroll
  for (int off = 32; off > 0; off >>= 1) s += __shfl_down(s, off);
  if ((tid & 63) == 0) red[tid >> 6] = s;
  __syncthreads();
  if (tid == 0) labels[c] = red[0] + red[1] + red[2] + red[3] + bout[0];
}

__global__ void loss_kernel(const float* __restrict__ labels, float* __restrict__ out)
{
  const int tid = threadIdx.x;    // 128 threads
  __shared__ float rg[2], rt[2];
  float v = labels[tid];
  float g = (tid < 64) ? v : 0.f;
  float t = (tid >= 64) ? v : 0.f;
#pragma unroll
  for (int off = 32; off > 0; off >>= 1) {
    g += __shfl_down(g, off);
    t += __shfl_down(t, off);
  }
  if ((tid & 63) == 0) { rg[tid >> 6] = g; rt[tid >> 6] = t; }
  __syncthreads();
  if (tid == 0) {
    float gm = (rg[0] + rg[1]) * (1.f / 64.f);
    float tm = (rt[0] + rt[1]) * (1.f / 64.f);
    out[0] = -tm + gm;
    out[1] = -gm;
  }
}

// ---------------------------------------------------------------------------
extern "C" void kernel_launch(void* const* d_in, const int* in_sizes, int n_in,
                              void* d_out, int out_size, void* d_ws, size_t ws_size,
                              hipStream_t stream)
{
  const float* gen  = (const float*)d_in[0];
  const float* tru  = (const float*)d_in[1];
  const float* Wih0 = (const float*)d_in[2];
  const float* Whh0 = (const float*)d_in[3];
  const float* bih0 = (const float*)d_in[4];
  const float* bhh0 = (const float*)d_in[5];
  const float* gig0 = (const float*)d_in[6];
  const float* gib0 = (const float*)d_in[7];
  const float* ghg0 = (const float*)d_in[8];
  const float* ghb0 = (const float*)d_in[9];
  const float* Wih1 = (const float*)d_in[10];
  const float* Whh1 = (const float*)d_in[11];
  const float* bih1 = (const float*)d_in[12];
  const float* bhh1 = (const float*)d_in[13];
  const float* gig1 = (const float*)d_in[14];
  const float* gib1 = (const float*)d_in[15];
  const float* ghg1 = (const float*)d_in[16];
  const float* ghb1 = (const float*)d_in[17];
  const float* Wout = (const float*)d_in[18];
  const float* bout = (const float*)d_in[19];
  float* out = (float*)d_out;

  // Runtime-adaptive time-chunk size: largest power-of-two Tc (<=256) whose
  // footprint fits ws_size. Footprint (floats):
  //   pi_chunk  NCH*Tc*N3   (shared between layer0 and layer1 phases)
  //   h0_chunk  NCH*Tc*HDIM
  //   ahp       4*NCH*N3
  //   h_cur0/1  2*NCH*HDIM
  //   labels    128 (+pad)
  const size_t fixedF = (size_t)4 * NCH * N3 + 2 * (size_t)NCH * HDIM + 256;
  int Tc = 256;
  while (Tc > 1) {
    size_t needF = (size_t)NCH * Tc * (N3 + HDIM) + fixedF;
    if (needF * 4 <= ws_size) break;
    Tc >>= 1;
  }
  int lTc = 0;
  while ((1 << lTc) < Tc) ++lTc;

  float* ws       = (float*)d_ws;
  float* pi_chunk = ws;                                     // NCH*Tc*N3
  float* h0_chunk = pi_chunk + (size_t)NCH * Tc * N3;       // NCH*Tc*HDIM
  float* ahp      = h0_chunk + (size_t)NCH * Tc * HDIM;     // 4*NCH*N3
  float* h_cur0   = ahp + (size_t)4 * NCH * N3;             // NCH*HDIM
  float* h_cur1   = h_cur0 + (size_t)NCH * HDIM;            // NCH*HDIM
  float* labels   = h_cur1 + (size_t)NCH * HDIM;            // 128

  zero_kernel<<<(2 * NCH * HDIM) / 256, 256, 0, stream>>>(h_cur0, 2 * NCH * HDIM);

  const int nChunks = SLEN / Tc;
  for (int cidx = 0; cidx < nChunks; ++cidx) {
    const int t0 = cidx * Tc;
    // ---- layer 0: xproj + LN for this time-chunk ----
    xproj_gemm<<<dim3(24, Tc), 256, 0, stream>>>(
        gen, tru, 64, SLEN, t0, 512, lTc, Wih0, bih0, pi_chunk);
    ln_rows<<<NCH * Tc, 256, 0, stream>>>(pi_chunk, gig0, gib0);
    // ---- layer 0: recurrence over the chunk ----
    for (int dt = 0; dt < Tc; ++dt) {
      gemm_step<<<dim3(48, 4), 256, 0, stream>>>(h_cur0, Whh0, ahp);
      lngate_step<<<NCH, 256, 0, stream>>>(ahp, bhh0, ghg0, ghb0,
                                           pi_chunk, Tc, dt, h_cur0, h0_chunk);
    }
    // ---- layer 1: xproj + LN from h0_chunk (reuses pi_chunk buffer) ----
    xproj_gemm<<<dim3(24, Tc), 256, 0, stream>>>(
        h0_chunk, h0_chunk, NCH, Tc, 0, 1024, lTc, Wih1, bih1, pi_chunk);
    ln_rows<<<NCH * Tc, 256, 0, stream>>>(pi_chunk, gig1, gib1);
    // ---- layer 1: recurrence over the chunk ----
    for (int dt = 0; dt < Tc; ++dt) {
      gemm_step<<<dim3(48, 4), 256, 0, stream>>>(h_cur1, Whh1, ahp);
      lngate_step<<<NCH, 256, 0, stream>>>(ahp, bhh1, ghg1, ghb1,
                                           pi_chunk, Tc, dt, h_cur1, nullptr);
    }
  }

  // ---- readout ----
  label_kernel<<<NCH, 256, 0, stream>>>(h_cur1, Wout, bout, labels);
  loss_kernel<<<1, 128, 0, stream>>>(labels, out);
}

// Round 3
// 15001.395 us; speedup vs baseline: 1.3133x; 1.3133x over previous
//
#include <hip/hip_runtime.h>
#include <math.h>

#define NCH   128          // chains = 2*B (0..63 = generated, 64..127 = true)
#define SLEN  256
#define HDIM  1024
#define N3    3072

typedef __attribute__((ext_vector_type(8))) __bf16 bf16x8;
typedef __attribute__((ext_vector_type(4))) __bf16 bf16x4;
typedef __attribute__((ext_vector_type(4))) float  f32x4;

__device__ __forceinline__ f32x4 mfma_bf16(bf16x8 a, bf16x8 b, f32x4 c) {
  return __builtin_amdgcn_mfma_f32_16x16x32_bf16(a, b, c, 0, 0, 0);
}

// ---------------------------------------------------------------------------
// split_w: fp32 -> (hi, lo) bf16 pair, elementwise.
// ---------------------------------------------------------------------------
__global__ void split_w(const float* __restrict__ src, __bf16* __restrict__ dh,
                        __bf16* __restrict__ dl, int n)
{
  int i = blockIdx.x * blockDim.x + threadIdx.x;
  if (i < n) {
    float x = src[i];
    __bf16 h = (__bf16)x;
    float r = x - (float)h;
    dh[i] = h;
    dl[i] = (__bf16)r;
  }
}

__global__ void zero_kernel(float* __restrict__ p, int n)
{
  int i = blockIdx.x * blockDim.x + threadIdx.x;
  if (i < n) p[i] = 0.f;
}

// ---------------------------------------------------------------------------
// xproj_mfma: out[r, n] = x_row(r) @ W[n, :] + bias[n], split-bf16 3-pass MFMA.
// Block: 256 thr, tile 128(M) x 64(N); wave tile 32x64 (2m x 4n MFMA tiles).
// A staged fp32->hi/lo in LDS (fragment-major [quad][m][8]); B frags direct
// from pre-split global W ([n][K] row-major -> 8 contiguous k per lane).
// Row mapping: chain = r>>lTc, dt = r&(Tc-1); src row chain*strideChain+t0+dt.
// ---------------------------------------------------------------------------
__global__ __launch_bounds__(256) void xproj_mfma(
    const float* __restrict__ A0, const float* __restrict__ A1,
    int chainsA0, int strideChain, int t0, int K, int lTc,
    const __bf16* __restrict__ Wh, const __bf16* __restrict__ Wl,
    const float* __restrict__ bias, float* __restrict__ out)
{
  __shared__ __bf16 Ah[4][128][8];
  __shared__ __bf16 Al[4][128][8];
  const int tid  = threadIdx.x;
  const int n0   = blockIdx.x * 64;
  const int row0 = blockIdx.y * 128;
  const int lane = tid & 63;
  const int wv   = tid >> 6;
  const int q    = lane >> 4;
  const int c15  = lane & 15;
  const int m_off = wv * 32;
  // staging: thread -> row sr, k-halves
  const int sr  = tid >> 1;
  const int sq0 = (tid & 1) * 2;
  const int sk  = (tid & 1) * 16;
  const int r     = row0 + sr;
  const int chain = r >> lTc;
  const int dt    = r & ((1 << lTc) - 1);
  const float* aptr = (chain < chainsA0)
      ? (A0 + ((size_t)chain * strideChain + t0 + dt) * K)
      : (A1 + ((size_t)(chain - chainsA0) * strideChain + t0 + dt) * K);

  f32x4 acc[2][4];
#pragma unroll
  for (int i = 0; i < 2; ++i)
#pragma unroll
    for (int j = 0; j < 4; ++j) acc[i][j] = (f32x4){0.f, 0.f, 0.f, 0.f};

  for (int k0 = 0; k0 < K; k0 += 32) {
    float f[16];
    *(float4*)(f + 0)  = *(const float4*)(aptr + k0 + sk + 0);
    *(float4*)(f + 4)  = *(const float4*)(aptr + k0 + sk + 4);
    *(float4*)(f + 8)  = *(const float4*)(aptr + k0 + sk + 8);
    *(float4*)(f + 12) = *(const float4*)(aptr + k0 + sk + 12);
    bf16x8 hv0, hv1, lv0, lv1;
#pragma unroll
    for (int e = 0; e < 8; ++e) {
      __bf16 h0 = (__bf16)f[e];
      hv0[e] = h0;  lv0[e] = (__bf16)(f[e] - (float)h0);
      __bf16 h1 = (__bf16)f[8 + e];
      hv1[e] = h1;  lv1[e] = (__bf16)(f[8 + e] - (float)h1);
    }
    __syncthreads();
    *(bf16x8*)&Ah[sq0][sr][0]     = hv0;
    *(bf16x8*)&Ah[sq0 + 1][sr][0] = hv1;
    *(bf16x8*)&Al[sq0][sr][0]     = lv0;
    *(bf16x8*)&Al[sq0 + 1][sr][0] = lv1;
    __syncthreads();

    bf16x8 a_h[2], a_l[2];
#pragma unroll
    for (int i = 0; i < 2; ++i) {
      a_h[i] = *(const bf16x8*)&Ah[q][m_off + i * 16 + c15][0];
      a_l[i] = *(const bf16x8*)&Al[q][m_off + i * 16 + c15][0];
    }
#pragma unroll
    for (int j = 0; j < 4; ++j) {
      const size_t woff = (size_t)(n0 + j * 16 + c15) * K + k0 + q * 8;
      bf16x8 b_h = *(const bf16x8*)(Wh + woff);
      bf16x8 b_l = *(const bf16x8*)(Wl + woff);
#pragma unroll
      for (int i = 0; i < 2; ++i) {
        acc[i][j] = mfma_bf16(a_h[i], b_h, acc[i][j]);
        acc[i][j] = mfma_bf16(a_h[i], b_l, acc[i][j]);
        acc[i][j] = mfma_bf16(a_l[i], b_h, acc[i][j]);
      }
    }
  }

#pragma unroll
  for (int j = 0; j < 4; ++j) {
    const int col = n0 + j * 16 + c15;
    const float bcol = bias[col];
#pragma unroll
    for (int i = 0; i < 2; ++i) {
#pragma unroll
      for (int rr = 0; rr < 4; ++rr) {
        const int m = m_off + i * 16 + q * 4 + rr;
        out[(size_t)(row0 + m) * N3 + col] = acc[i][j][rr] + bcol;
      }
    }
  }
}

// ---------------------------------------------------------------------------
// ln_rows: in-place LayerNorm per gate over H for each row of [rows, 3, H].
// ---------------------------------------------------------------------------
__global__ __launch_bounds__(256) void ln_rows(float* __restrict__ a,
    const float* __restrict__ gw, const float* __restrict__ gb)
{
  const int row = blockIdx.x;
  const int tid = threadIdx.x;
  float* base = a + (size_t)row * N3;
  __shared__ float redS[4], redS2[4];
  __shared__ float s_mean, s_rstd;
  for (int g = 0; g < 3; ++g) {
    const int j = g * 1024 + tid * 4;
    float4 v = *(const float4*)(base + j);
    float s  = v.x + v.y + v.z + v.w;
    float s2 = v.x*v.x + v.y*v.y + v.z*v.z + v.w*v.w;
#pragma unroll
    for (int off = 32; off > 0; off >>= 1) {
      s  += __shfl_down(s, off);
      s2 += __shfl_down(s2, off);
    }
    if ((tid & 63) == 0) { redS[tid >> 6] = s; redS2[tid >> 6] = s2; }
    __syncthreads();
    if (tid == 0) {
      float S  = redS[0] + redS[1] + redS[2] + redS[3];
      float S2 = redS2[0] + redS2[1] + redS2[2] + redS2[3];
      float mean = S * (1.f / 1024.f);
      float var  = S2 * (1.f / 1024.f) - mean * mean;
      s_mean = mean;
      s_rstd = rsqrtf(var + 1e-5f);
    }
    __syncthreads();
    float mean = s_mean, rstd = s_rstd;
    float4 gwv = *(const float4*)(gw + j);
    float4 gbv = *(const float4*)(gb + j);
    float4 o;
    o.x = (v.x - mean) * rstd * gwv.x + gbv.x;
    o.y = (v.y - mean) * rstd * gwv.y + gbv.y;
    o.z = (v.z - mean) * rstd * gwv.z + gbv.z;
    o.w = (v.w - mean) * rstd * gwv.w + gbv.w;
    *(float4*)(base + j) = o;
    __syncthreads();
  }
}

// ---------------------------------------------------------------------------
// gemm_step_mfma: ah_part[kc][m][n] = h[m, kc*512:+512] @ Whh[n, same]^T
// Split-K=2, grid (96,2). Block 256 thr, tile 128(M) x 32(N); wave 32x32
// (2m x 2n). No LDS: h hi/lo (256 KB, L2-hot) and W hi/lo read as 16 B
// fragments directly from global. 3-pass split-bf16 accumulate in fp32.
// ---------------------------------------------------------------------------
__global__ __launch_bounds__(256) void gemm_step_mfma(
    const __bf16* __restrict__ Hh, const __bf16* __restrict__ Hl,
    const __bf16* __restrict__ Wh, const __bf16* __restrict__ Wl,
    float* __restrict__ ah_part)
{
  const int tid  = threadIdx.x;
  const int n0   = blockIdx.x * 32;
  const int kc   = blockIdx.y;        // 0..1
  const int lane = tid & 63;
  const int wv   = tid >> 6;
  const int q    = lane >> 4;
  const int c15  = lane & 15;
  const int m_off = wv * 32;

  f32x4 acc[2][2];
#pragma unroll
  for (int i = 0; i < 2; ++i)
#pragma unroll
    for (int j = 0; j < 2; ++j) acc[i][j] = (f32x4){0.f, 0.f, 0.f, 0.f};

  const size_t arow0 = (size_t)(m_off + c15) * HDIM;
  const size_t arow1 = (size_t)(m_off + 16 + c15) * HDIM;
  const size_t brow0 = (size_t)(n0 + c15) * HDIM;
  const size_t brow1 = (size_t)(n0 + 16 + c15) * HDIM;
  const int kb = kc * 512;

#pragma unroll 4
  for (int k0 = 0; k0 < 512; k0 += 32) {
    const int k = kb + k0 + q * 8;
    bf16x8 ah0 = *(const bf16x8*)(Hh + arow0 + k);
    bf16x8 ah1 = *(const bf16x8*)(Hh + arow1 + k);
    bf16x8 al0 = *(const bf16x8*)(Hl + arow0 + k);
    bf16x8 al1 = *(const bf16x8*)(Hl + arow1 + k);
    bf16x8 bh0 = *(const bf16x8*)(Wh + brow0 + k);
    bf16x8 bh1 = *(const bf16x8*)(Wh + brow1 + k);
    bf16x8 bl0 = *(const bf16x8*)(Wl + brow0 + k);
    bf16x8 bl1 = *(const bf16x8*)(Wl + brow1 + k);
    acc[0][0] = mfma_bf16(ah0, bh0, acc[0][0]);
    acc[0][1] = mfma_bf16(ah0, bh1, acc[0][1]);
    acc[1][0] = mfma_bf16(ah1, bh0, acc[1][0]);
    acc[1][1] = mfma_bf16(ah1, bh1, acc[1][1]);
    acc[0][0] = mfma_bf16(ah0, bl0, acc[0][0]);
    acc[0][1] = mfma_bf16(ah0, bl1, acc[0][1]);
    acc[1][0] = mfma_bf16(ah1, bl0, acc[1][0]);
    acc[1][1] = mfma_bf16(ah1, bl1, acc[1][1]);
    acc[0][0] = mfma_bf16(al0, bh0, acc[0][0]);
    acc[0][1] = mfma_bf16(al0, bh1, acc[0][1]);
    acc[1][0] = mfma_bf16(al1, bh0, acc[1][0]);
    acc[1][1] = mfma_bf16(al1, bh1, acc[1][1]);
  }

#pragma unroll
  for (int i = 0; i < 2; ++i)
#pragma unroll
    for (int j = 0; j < 2; ++j) {
      const int n = n0 + j * 16 + c15;
#pragma unroll
      for (int rr = 0; rr < 4; ++rr) {
        const int m = m_off + i * 16 + q * 4 + rr;
        ah_part[(size_t)(kc * 128 + m) * N3 + n] = acc[i][j][rr];
      }
    }
}

// ---------------------------------------------------------------------------
// lngate_step: per chain -- sum 2 split-K partials + bhh, LN per gate, combine
// with pi row (chain*Tc + dt), GRU gates. Writes h fp32 + hi/lo bf16
// (+ optional fp32 h-seq row for the next layer's xproj).
// ---------------------------------------------------------------------------
__global__ __launch_bounds__(256) void lngate_step(
    const float* __restrict__ ah_part, const float* __restrict__ bhh,
    const float* __restrict__ ghw, const float* __restrict__ ghb,
    const float* __restrict__ pi, int Tc, int dt, float* __restrict__ h_cur,
    __bf16* __restrict__ Hh, __bf16* __restrict__ Hl, float* __restrict__ hseq)
{
  const int c   = blockIdx.x;
  const int tid = threadIdx.x;
  __shared__ __align__(16) float sa[N3];
  __shared__ float redS[4], redS2[4];
  __shared__ float stats[3][2];

#pragma unroll
  for (int p = 0; p < 3; ++p) {
    const int n = p * 1024 + tid * 4;
    float4 v0 = *(const float4*)(ah_part + (size_t)c * N3 + n);
    float4 v1 = *(const float4*)(ah_part + (size_t)(128 + c) * N3 + n);
    float4 bb = *(const float4*)(bhh + n);
    float4 s;
    s.x = v0.x + v1.x + bb.x;
    s.y = v0.y + v1.y + bb.y;
    s.z = v0.z + v1.z + bb.z;
    s.w = v0.w + v1.w + bb.w;
    *(float4*)(sa + n) = s;
  }
  __syncthreads();

  for (int g = 0; g < 3; ++g) {
    float4 v = *(const float4*)(sa + g * 1024 + tid * 4);
    float s  = v.x + v.y + v.z + v.w;
    float s2 = v.x*v.x + v.y*v.y + v.z*v.z + v.w*v.w;
#pragma unroll
    for (int off = 32; off > 0; off >>= 1) {
      s  += __shfl_down(s, off);
      s2 += __shfl_down(s2, off);
    }
    if ((tid & 63) == 0) { redS[tid >> 6] = s; redS2[tid >> 6] = s2; }
    __syncthreads();
    if (tid == 0) {
      float S  = redS[0] + redS[1] + redS[2] + redS[3];
      float S2 = redS2[0] + redS2[1] + redS2[2] + redS2[3];
      float mean = S * (1.f / 1024.f);
      float var  = S2 * (1.f / 1024.f) - mean * mean;
      stats[g][0] = mean;
      stats[g][1] = rsqrtf(var + 1e-5f);
    }
    __syncthreads();
  }

  const int j = tid * 4;
  float ar[4], az[4], an[4];
  *(float4*)ar = *(const float4*)(sa + j);
  *(float4*)az = *(const float4*)(sa + 1024 + j);
  *(float4*)an = *(const float4*)(sa + 2048 + j);
  float gwr[4], gbr[4], gwz[4], gbz[4], gwn[4], gbn[4];
  *(float4*)gwr = *(const float4*)(ghw + j);
  *(float4*)gbr = *(const float4*)(ghb + j);
  *(float4*)gwz = *(const float4*)(ghw + 1024 + j);
  *(float4*)gbz = *(const float4*)(ghb + 1024 + j);
  *(float4*)gwn = *(const float4*)(ghw + 2048 + j);
  *(float4*)gbn = *(const float4*)(ghb + 2048 + j);
  const float* pirow = pi + ((size_t)c * Tc + dt) * N3;
  float pr[4], pz[4], pn[4], hp[4], hn[4];
  *(float4*)pr = *(const float4*)(pirow + j);
  *(float4*)pz = *(const float4*)(pirow + 1024 + j);
  *(float4*)pn = *(const float4*)(pirow + 2048 + j);
  *(float4*)hp = *(const float4*)(h_cur + (size_t)c * HDIM + j);
  const float mr = stats[0][0], rr = stats[0][1];
  const float mz = stats[1][0], rz = stats[1][1];
  const float mn = stats[2][0], rn = stats[2][1];
  bf16x4 hh, hl;
#pragma unroll
  for (int qq = 0; qq < 4; ++qq) {
    float phr = (ar[qq] - mr) * rr * gwr[qq] + gbr[qq];
    float phz = (az[qq] - mz) * rz * gwz[qq] + gbz[qq];
    float phn = (an[qq] - mn) * rn * gwn[qq] + gbn[qq];
    float r = 1.f / (1.f + expf(-(pr[qq] + phr)));
    float z = 1.f / (1.f + expf(-(pz[qq] + phz)));
    float nn = tanhf(pn[qq] + r * phn);
    hn[qq] = (1.f - z) * nn + z * hp[qq];
    __bf16 hb = (__bf16)hn[qq];
    hh[qq] = hb;
    hl[qq] = (__bf16)(hn[qq] - (float)hb);
  }
  *(float4*)(h_cur + (size_t)c * HDIM + j) = *(float4*)hn;
  *(bf16x4*)(Hh + (size_t)c * HDIM + j) = hh;
  *(bf16x4*)(Hl + (size_t)c * HDIM + j) = hl;
  if (hseq)
    *(float4*)(hseq + ((size_t)c * Tc + dt) * HDIM + j) = *(float4*)hn;
}

// ---------------------------------------------------------------------------
__global__ __launch_bounds__(256) void label_kernel(const float* __restrict__ h,
    const float* __restrict__ Wout, const float* __restrict__ bout,
    float* __restrict__ labels)
{
  const int c = blockIdx.x;
  const int tid = threadIdx.x;
  __shared__ float red[4];
  float4 hv = *(const float4*)(h + (size_t)c * HDIM + tid * 4);
  float4 wv = *(const float4*)(Wout + tid * 4);
  float s = hv.x * wv.x + hv.y * wv.y + hv.z * wv.z + hv.w * wv.w;
#pragma unroll
  for (int off = 32; off > 0; off >>= 1) s += __shfl_down(s, off);
  if ((tid & 63) == 0) red[tid >> 6] = s;
  __syncthreads();
  if (tid == 0) labels[c] = red[0] + red[1] + red[2] + red[3] + bout[0];
}

__global__ void loss_kernel(const float* __restrict__ labels, float* __restrict__ out)
{
  const int tid = threadIdx.x;    // 128 threads
  __shared__ float rg[2], rt[2];
  float v = labels[tid];
  float g = (tid < 64) ? v : 0.f;
  float t = (tid >= 64) ? v : 0.f;
#pragma unroll
  for (int off = 32; off > 0; off >>= 1) {
    g += __shfl_down(g, off);
    t += __shfl_down(t, off);
  }
  if ((tid & 63) == 0) { rg[tid >> 6] = g; rt[tid >> 6] = t; }
  __syncthreads();
  if (tid == 0) {
    float gm = (rg[0] + rg[1]) * (1.f / 64.f);
    float tm = (rt[0] + rt[1]) * (1.f / 64.f);
    out[0] = -tm + gm;
    out[1] = -gm;
  }
}

// ---------------------------------------------------------------------------
extern "C" void kernel_launch(void* const* d_in, const int* in_sizes, int n_in,
                              void* d_out, int out_size, void* d_ws, size_t ws_size,
                              hipStream_t stream)
{
  const float* gen  = (const float*)d_in[0];
  const float* tru  = (const float*)d_in[1];
  const float* Wih0 = (const float*)d_in[2];
  const float* Whh0 = (const float*)d_in[3];
  const float* bih0 = (const float*)d_in[4];
  const float* bhh0 = (const float*)d_in[5];
  const float* gig0 = (const float*)d_in[6];
  const float* gib0 = (const float*)d_in[7];
  const float* ghg0 = (const float*)d_in[8];
  const float* ghb0 = (const float*)d_in[9];
  const float* Wih1 = (const float*)d_in[10];
  const float* Whh1 = (const float*)d_in[11];
  const float* bih1 = (const float*)d_in[12];
  const float* bhh1 = (const float*)d_in[13];
  const float* gig1 = (const float*)d_in[14];
  const float* gib1 = (const float*)d_in[15];
  const float* ghg1 = (const float*)d_in[16];
  const float* ghb1 = (const float*)d_in[17];
  const float* Wout = (const float*)d_in[18];
  const float* bout = (const float*)d_in[19];
  float* out = (float*)d_out;

  // ---- bf16 hi/lo region (shorts) ----
  __bf16* bp = (__bf16*)d_ws;
  __bf16* Whh0h = bp;                 bp += (size_t)N3 * HDIM;
  __bf16* Whh0l = bp;                 bp += (size_t)N3 * HDIM;
  __bf16* Whh1h = bp;                 bp += (size_t)N3 * HDIM;
  __bf16* Whh1l = bp;                 bp += (size_t)N3 * HDIM;
  __bf16* Wih1h = bp;                 bp += (size_t)N3 * HDIM;
  __bf16* Wih1l = bp;                 bp += (size_t)N3 * HDIM;
  __bf16* Wih0h = bp;                 bp += (size_t)N3 * 512;
  __bf16* Wih0l = bp;                 bp += (size_t)N3 * 512;
  __bf16* hbf   = bp;                 bp += (size_t)4 * NCH * HDIM; // [layer][h/l][NCH*HDIM]
  const size_t bf16Bytes = (size_t)((char*)bp - (char*)d_ws);

  // ---- float region ----
  // pi_chunk NCH*Tc*N3 | h0_chunk NCH*Tc*HDIM | ahp 2*NCH*N3 | h_cur 2*NCH*HDIM | labels
  const size_t fixedF = (size_t)2 * NCH * N3 + 2 * (size_t)NCH * HDIM + 256;
  int Tc = 256;
  while (Tc > 1) {
    size_t needB = bf16Bytes + 4 * ((size_t)NCH * Tc * (N3 + HDIM) + fixedF);
    if (needB <= ws_size) break;
    Tc >>= 1;
  }
  int lTc = 0;
  while ((1 << lTc) < Tc) ++lTc;

  float* fp       = (float*)((char*)d_ws + bf16Bytes);
  float* pi_chunk = fp;                                     fp += (size_t)NCH * Tc * N3;
  float* h0_chunk = fp;                                     fp += (size_t)NCH * Tc * HDIM;
  float* ahp      = fp;                                     fp += (size_t)2 * NCH * N3;
  float* h_cur0   = fp;                                     fp += (size_t)NCH * HDIM;
  float* h_cur1   = fp;                                     fp += (size_t)NCH * HDIM;
  float* labels   = fp;

  __bf16* H0h = hbf;
  __bf16* H0l = hbf + (size_t)NCH * HDIM;
  __bf16* H1h = hbf + (size_t)2 * NCH * HDIM;
  __bf16* H1l = hbf + (size_t)3 * NCH * HDIM;

  // ---- weight split (once per launch) ----
  {
    const int nW = N3 * HDIM;
    split_w<<<(nW + 255) / 256, 256, 0, stream>>>(Whh0, Whh0h, Whh0l, nW);
    split_w<<<(nW + 255) / 256, 256, 0, stream>>>(Whh1, Whh1h, Whh1l, nW);
    split_w<<<(nW + 255) / 256, 256, 0, stream>>>(Wih1, Wih1h, Wih1l, nW);
    const int nW0 = N3 * 512;
    split_w<<<(nW0 + 255) / 256, 256, 0, stream>>>(Wih0, Wih0h, Wih0l, nW0);
  }
  // zero h states (fp32 pair + bf16 pairs viewed as floats)
  zero_kernel<<<(2 * NCH * HDIM) / 256, 256, 0, stream>>>(h_cur0, 2 * NCH * HDIM);
  zero_kernel<<<(2 * NCH * HDIM) / 256, 256, 0, stream>>>((float*)hbf, 2 * NCH * HDIM);

  const int nChunks = SLEN / Tc;
  for (int cidx = 0; cidx < nChunks; ++cidx) {
    const int t0 = cidx * Tc;
    // ---- layer 0: xproj + LN for this time-chunk ----
    xproj_mfma<<<dim3(48, Tc), 256, 0, stream>>>(
        gen, tru, 64, SLEN, t0, 512, lTc, Wih0h, Wih0l, bih0, pi_chunk);
    ln_rows<<<NCH * Tc, 256, 0, stream>>>(pi_chunk, gig0, gib0);
    // ---- layer 0 recurrence ----
    for (int dt = 0; dt < Tc; ++dt) {
      gemm_step_mfma<<<dim3(96, 2), 256, 0, stream>>>(H0h, H0l, Whh0h, Whh0l, ahp);
      lngate_step<<<NCH, 256, 0, stream>>>(ahp, bhh0, ghg0, ghb0,
                                           pi_chunk, Tc, dt, h_cur0, H0h, H0l, h0_chunk);
    }
    // ---- layer 1: xproj + LN from h0_chunk ----
    xproj_mfma<<<dim3(48, Tc), 256, 0, stream>>>(
        h0_chunk, h0_chunk, NCH, Tc, 0, 1024, lTc, Wih1h, Wih1l, bih1, pi_chunk);
    ln_rows<<<NCH * Tc, 256, 0, stream>>>(pi_chunk, gig1, gib1);
    // ---- layer 1 recurrence ----
    for (int dt = 0; dt < Tc; ++dt) {
      gemm_step_mfma<<<dim3(96, 2), 256, 0, stream>>>(H1h, H1l, Whh1h, Whh1l, ahp);
      lngate_step<<<NCH, 256, 0, stream>>>(ahp, bhh1, ghg1, ghb1,
                                           pi_chunk, Tc, dt, h_cur1, H1h, H1l, nullptr);
    }
  }

  // ---- readout ----
  label_kernel<<<NCH, 256, 0, stream>>>(h_cur1, Wout, bout, labels);
  loss_kernel<<<1, 128, 0, stream>>>(labels, out);
}